// Round 2
// baseline (243.626 us; speedup 1.0000x reference)
//
#include <hip/hip_runtime.h>

#define TILE 32
#define CH 64

__device__ __forceinline__ const float* row_ptr(const float* __restrict__ src,
                                                const float* __restrict__ tgt,
                                                int g, int ns, int D) {
    return (g < ns) ? (src + (size_t)g * D) : (tgt + (size_t)(g - ns) * D);
}

// Label building: t_hard = argmax(t_label), per-class counts + row lists.
__global__ void k_prep(const int* __restrict__ slab, const float* __restrict__ tlab,
                       int ns, int N, int C,
                       int* __restrict__ clsrows, int* __restrict__ cnt_src,
                       int* __restrict__ fill) {
    int i = blockIdx.x * 256 + threadIdx.x;
    if (i >= N) return;
    int lab;
    if (i < ns) {
        lab = slab[i];
    } else {
        const float* row = tlab + (size_t)(i - ns) * C;
        float best = row[0];
        lab = 0;
        for (int c = 1; c < C; c++) {
            float v = row[c];
            if (v > best) { best = v; lab = c; }   // strict > : first-max (jnp.argmax)
        }
    }
    if (i < ns) atomicAdd(&cnt_src[lab], 1);
    int pos = atomicAdd(&fill[lab], 1);
    clsrows[(size_t)lab * N + pos] = i;
}

// sq[i] = sum_d x[i][d]^2
__global__ void k_rowsq(const float* __restrict__ src, const float* __restrict__ tgt,
                        int ns, int D, float* __restrict__ sqv) {
    int i = blockIdx.x;
    const float* row = row_ptr(src, tgt, i, ns, D);
    float s = 0.f;
    for (int d = threadIdx.x * 4; d < D; d += 256 * 4) {
        float4 v = *(const float4*)(row + d);
        s += v.x * v.x + v.y * v.y + v.z * v.z + v.w * v.w;
    }
    for (int o = 32; o; o >>= 1) s += __shfl_down(s, o);
    __shared__ float ls[4];
    if ((threadIdx.x & 63) == 0) ls[threadIdx.x >> 6] = s;
    __syncthreads();
    if (threadIdx.x == 0) sqv[i] = ls[0] + ls[1] + ls[2] + ls[3];
}

// sqsum[c] = sum_{i in c} sq[i]
__global__ void k_class_sq(const int* __restrict__ clsrows, const int* __restrict__ fill,
                           const float* __restrict__ sqv, int N, double* __restrict__ sqsum) {
    int c = blockIdx.x;
    int n = fill[c];
    const int* rows = clsrows + (size_t)c * N;
    float s = 0.f;
    for (int k = threadIdx.x; k < n; k += 256) s += sqv[rows[k]];
    for (int o = 32; o; o >>= 1) s += __shfl_down(s, o);
    __shared__ float ls[4];
    if ((threadIdx.x & 63) == 0) ls[threadIdx.x >> 6] = s;
    __syncthreads();
    if (threadIdx.x == 0) sqsum[c] = (double)(ls[0] + ls[1] + ls[2] + ls[3]);
}

// snorm2[c] = || sum_{i in c} x_i ||^2   (accumulated per 256-col chunk)
__global__ void k_snorm(const float* __restrict__ src, const float* __restrict__ tgt,
                        const int* __restrict__ clsrows, const int* __restrict__ fill,
                        int ns, int N, int D, double* __restrict__ snorm2) {
    int c = blockIdx.x;
    int d = blockIdx.y * 256 + threadIdx.x;
    int n = fill[c];
    const int* rows = clsrows + (size_t)c * N;
    float s = 0.f;
    if (d < D) {
        for (int k = 0; k < n; k++) {
            int g = rows[k];
            s += row_ptr(src, tgt, g, ns, D)[d];
        }
    }
    double s2 = (double)s * (double)s;
    for (int o = 32; o; o >>= 1) s2 += __shfl_down(s2, o);
    __shared__ double ls[4];
    if ((threadIdx.x & 63) == 0) ls[threadIdx.x >> 6] = s2;
    __syncthreads();
    if (threadIdx.x == 0) atomicAdd(&snorm2[c], ls[0] + ls[1] + ls[2] + ls[3]);
}

// Bandwidths + job table (prefix sum of per-class tile-pair counts).
__global__ void k_bw(const int* __restrict__ cnt_src, const int* __restrict__ fill,
                     const double* __restrict__ sqsum, const double* __restrict__ snorm2,
                     int C,
                     float* __restrict__ invbw, double* __restrict__ inv_n2,
                     int* __restrict__ present, int* __restrict__ jobOff,
                     int* __restrict__ tilesC, int* __restrict__ nJobsP) {
    __shared__ int tiles_s[64];
    int c = threadIdx.x;
    if (c < C) {
        int n_src = cnt_src[c];
        int n = fill[c];
        int n_tgt = n - n_src;
        int pres = (n_src > 0 && n_tgt > 0) ? 1 : 0;
        present[c] = pres;
        double l2sum = 2.0 * (double)n * sqsum[c] - 2.0 * snorm2[c];
        double denom = (double)n * (double)n - (double)n;
        if (denom < 1.0) denom = 1.0;
        double bw = l2sum / denom / 4.0;            // bw_scale = KERNEL_MUL^(KERNEL_NUM//2) = 4
        bw = pres ? fmax(bw, 1e-20) : 1.0;
        double nn = (double)n * (double)n;
        if (nn < 1.0) nn = 1.0;
        inv_n2[c] = 1.0 / nn;
        double m = 1.0;
        for (int k = 0; k < 5; k++) { invbw[c * 8 + k] = (float)(1.0 / (bw * m)); m *= 2.0; }
        int T = pres ? (n + TILE - 1) / TILE : 0;
        tilesC[c] = T;
        tiles_s[c] = T * T;
    }
    __syncthreads();
    if (c == 0) {
        int acc = 0;
        for (int i = 0; i < C; i++) { jobOff[i] = acc; acc += tiles_s[i]; }
        jobOff[C] = acc;
        *nJobsP = acc;
    }
}

// Pairwise kernel-sum: per job = (class, 32x32 pair tile).
__global__ __launch_bounds__(256) void k_pairs(
        const float* __restrict__ src, const float* __restrict__ tgt,
        const int* __restrict__ clsrows, const int* __restrict__ fill,
        const float* __restrict__ sqv, const float* __restrict__ invbw,
        const int* __restrict__ jobOff, const int* __restrict__ tilesC,
        const int* __restrict__ nJobsP,
        int ns, int N, int D, int C, double* __restrict__ contrib) {
    __shared__ float As[TILE][CH + 4];
    __shared__ float Bs[TILE][CH + 4];
    __shared__ int   rowsA[TILE], rowsB[TILE];
    __shared__ float sqA[TILE], sqB[TILE], sgA[TILE], sgB[TILE];

    int nJobs = *nJobsP;
    int tid = threadIdx.x;
    int pi = tid & 15, pj = tid >> 4;

    for (int job = blockIdx.x; job < nJobs; job += gridDim.x) {
        int c = 0;
        while (job >= jobOff[c + 1]) c++;
        int t = job - jobOff[c];
        int T = tilesC[c];
        int ti = t / T, tj = t % T;
        int n = fill[c];
        const int* rows = clsrows + (size_t)c * N;

        __syncthreads();   // protect smem from previous job
        if (tid < TILE) {
            int k = ti * TILE + tid;
            int g = (k < n) ? rows[k] : rows[0];
            rowsA[tid] = g; sqA[tid] = sqv[g]; sgA[tid] = (g < ns) ? 1.f : -1.f;
        } else if (tid < 2 * TILE) {
            int r = tid - TILE;
            int k = tj * TILE + r;
            int g = (k < n) ? rows[k] : rows[0];
            rowsB[r] = g; sqB[r] = sqv[g]; sgB[r] = (g < ns) ? 1.f : -1.f;
        }
        __syncthreads();

        float acc00 = 0.f, acc01 = 0.f, acc10 = 0.f, acc11 = 0.f;
        for (int d0 = 0; d0 < D; d0 += CH) {
            // stage CH cols of the 32 A-rows and 32 B-rows
            for (int s = 0; s < 2; s++) {
                int idx = tid + 256 * s;
                int r2 = idx >> 4;        // 0..31
                int q2 = idx & 15;        // 0..15 -> col q2*4
                const float* ra = row_ptr(src, tgt, rowsA[r2], ns, D);
                *(float4*)&As[r2][q2 * 4] = *(const float4*)(ra + d0 + q2 * 4);
                const float* rb = row_ptr(src, tgt, rowsB[r2], ns, D);
                *(float4*)&Bs[r2][q2 * 4] = *(const float4*)(rb + d0 + q2 * 4);
            }
            __syncthreads();
            #pragma unroll
            for (int d = 0; d < CH; d += 4) {
                float4 a0 = *(float4*)&As[pi][d];
                float4 a1 = *(float4*)&As[pi + 16][d];
                float4 b0 = *(float4*)&Bs[pj][d];
                float4 b1 = *(float4*)&Bs[pj + 16][d];
                acc00 += a0.x * b0.x + a0.y * b0.y + a0.z * b0.z + a0.w * b0.w;
                acc01 += a0.x * b1.x + a0.y * b1.y + a0.z * b1.z + a0.w * b1.w;
                acc10 += a1.x * b0.x + a1.y * b0.y + a1.z * b0.z + a1.w * b0.w;
                acc11 += a1.x * b1.x + a1.y * b1.y + a1.z * b1.z + a1.w * b1.w;
            }
            __syncthreads();
        }

        float ib0 = invbw[c * 8 + 0], ib1 = invbw[c * 8 + 1], ib2 = invbw[c * 8 + 2];
        float ib3 = invbw[c * 8 + 3], ib4 = invbw[c * 8 + 4];
        float tsum = 0.f;
        {
            int I, J; float a;
            #pragma unroll
            for (int q = 0; q < 4; q++) {
                if (q == 0) { I = pi;      J = pj;      a = acc00; }
                if (q == 1) { I = pi;      J = pj + 16; a = acc01; }
                if (q == 2) { I = pi + 16; J = pj;      a = acc10; }
                if (q == 3) { I = pi + 16; J = pj + 16; a = acc11; }
                if (ti * TILE + I < n && tj * TILE + J < n) {
                    float D2 = sqA[I] + sqB[J] - 2.f * a;
                    float e = expf(-D2 * ib0) + expf(-D2 * ib1) + expf(-D2 * ib2)
                            + expf(-D2 * ib3) + expf(-D2 * ib4);
                    tsum += sgA[I] * sgB[J] * e;
                }
            }
        }
        double dsum = (double)tsum;
        for (int o = 32; o; o >>= 1) dsum += __shfl_down(dsum, o);
        if ((tid & 63) == 0) atomicAdd(&contrib[c], dsum);
    }
}

__global__ void k_final(const double* __restrict__ contrib, const int* __restrict__ present,
                        const double* __restrict__ inv_n2, int C, float* __restrict__ out) {
    int c = threadIdx.x;
    double l = 0.0, k = 0.0;
    if (c < C && present[c]) { l = contrib[c] * inv_n2[c]; k = 1.0; }
    for (int o = 32; o; o >>= 1) { l += __shfl_down(l, o); k += __shfl_down(k, o); }
    if (c == 0) out[0] = (float)(l / k);
}

extern "C" void kernel_launch(void* const* d_in, const int* in_sizes, int n_in,
                              void* d_out, int out_size, void* d_ws, size_t ws_size,
                              hipStream_t stream) {
    const float* src  = (const float*)d_in[0];
    const float* tgt  = (const float*)d_in[1];
    const int*   slab = (const int*)d_in[2];
    const float* tlab = (const float*)d_in[3];
    const int ns = in_sizes[2];
    const int D  = in_sizes[0] / ns;
    const int nt = in_sizes[1] / D;
    const int C  = in_sizes[3] / nt;
    const int N  = ns + nt;

    char* w = (char*)d_ws;
    size_t off = 0;
    auto take = [&](size_t bytes) -> char* {
        char* p = w + off;
        off = (off + bytes + 255) & ~(size_t)255;
        return p;
    };
    // --- zero region (memset below) ---
    int*    cnt_src = (int*)take(C * sizeof(int));
    int*    fill    = (int*)take(C * sizeof(int));
    int*    nJobsP  = (int*)take(sizeof(int));
    double* snorm2  = (double*)take(C * sizeof(double));
    double* sqsum   = (double*)take(C * sizeof(double));
    double* contrib = (double*)take(C * sizeof(double));
    size_t zbytes = off;
    // --- rest ---
    int*    clsrows = (int*)take((size_t)C * N * sizeof(int));
    float*  sqv     = (float*)take((size_t)N * sizeof(float));
    float*  invbw   = (float*)take((size_t)C * 8 * sizeof(float));
    double* inv_n2  = (double*)take(C * sizeof(double));
    int*    present = (int*)take(C * sizeof(int));
    int*    jobOff  = (int*)take((C + 1) * sizeof(int));
    int*    tilesC  = (int*)take(C * sizeof(int));
    (void)ws_size; (void)n_in; (void)out_size;

    hipMemsetAsync(d_ws, 0, zbytes, stream);
    k_prep<<<(N + 255) / 256, 256, 0, stream>>>(slab, tlab, ns, N, C, clsrows, cnt_src, fill);
    k_rowsq<<<N, 256, 0, stream>>>(src, tgt, ns, D, sqv);
    k_class_sq<<<C, 256, 0, stream>>>(clsrows, fill, sqv, N, sqsum);
    dim3 g2(C, (D + 255) / 256);
    k_snorm<<<g2, 256, 0, stream>>>(src, tgt, clsrows, fill, ns, N, D, snorm2);
    k_bw<<<1, 64, 0, stream>>>(cnt_src, fill, sqsum, snorm2, C, invbw, inv_n2,
                               present, jobOff, tilesC, nJobsP);
    k_pairs<<<1024, 256, 0, stream>>>(src, tgt, clsrows, fill, sqv, invbw, jobOff,
                                      tilesC, nJobsP, ns, N, D, C, contrib);
    k_final<<<1, 64, 0, stream>>>(contrib, present, inv_n2, C, (float*)d_out);
}

// Round 3
// 152.779 us; speedup vs baseline: 1.5946x; 1.5946x over previous
//
#include <hip/hip_runtime.h>

typedef __attribute__((ext_vector_type(8))) short bf16x8;
typedef __attribute__((ext_vector_type(4))) float f32x4;

#define TILE 32

__device__ __forceinline__ unsigned int f2bf(float x) {
    unsigned int u = __float_as_uint(x);
    return (u + 0x7fffu + ((u >> 16) & 1u)) >> 16;   // RNE f32->bf16
}

// ---- labels: t_hard = argmax(t_label); per-class counts + row lists ----
__global__ void k_prep(const int* __restrict__ slab, const float* __restrict__ tlab,
                       int ns, int N, int C,
                       int* __restrict__ clsrows, int* __restrict__ cnt_src,
                       int* __restrict__ fill) {
    int i = blockIdx.x * 256 + threadIdx.x;
    if (i >= N) return;
    int lab;
    if (i < ns) {
        lab = slab[i];
    } else {
        const float* row = tlab + (size_t)(i - ns) * C;
        float best = row[0];
        lab = 0;
        for (int c = 1; c < C; c++) {
            float v = row[c];
            if (v > best) { best = v; lab = c; }   // strict >: first-max (jnp.argmax)
        }
    }
    if (i < ns) atomicAdd(&cnt_src[lab], 1);
    int pos = atomicAdd(&fill[lab], 1);
    clsrows[(size_t)lab * N + pos] = i;
}

// ---- prefix sums: row offsets, job table, presence, 1/n^2 (one wave) ----
__global__ void k_offsets(const int* __restrict__ cnt_src, const int* __restrict__ fill,
                          int C,
                          int* __restrict__ rowOff, int* __restrict__ jobOff,
                          int* __restrict__ tilesC, int* __restrict__ present,
                          double* __restrict__ inv_n2, int* __restrict__ nJobsP) {
    int lane = threadIdx.x;
    int n = (lane < C) ? fill[lane] : 0;
    int nsrc = (lane < C) ? cnt_src[lane] : 0;
    int pres = (nsrc > 0 && (n - nsrc) > 0) ? 1 : 0;
    int T = pres ? (n + TILE - 1) / TILE : 0;
    int jobs = T * T;
    int sn = n, sj = jobs;
    for (int o = 1; o < 64; o <<= 1) {
        int vn = __shfl_up(sn, o);
        int vj = __shfl_up(sj, o);
        if (lane >= o) { sn += vn; sj += vj; }
    }
    if (lane < C) {
        rowOff[lane] = sn - n;
        jobOff[lane] = sj - jobs;
        tilesC[lane] = T;
        present[lane] = pres;
        double nn = (double)n * (double)n;
        if (nn < 1.0) nn = 1.0;
        inv_n2[lane] = 1.0 / nn;
    }
    if (lane == C - 1) { rowOff[C] = sn; jobOff[C] = sj; *nJobsP = sj; }
}

// ---- gather rows class-contiguously as bf16; sq (f32) and sign per slot ----
__global__ __launch_bounds__(256) void k_gather(
        const float* __restrict__ src, const float* __restrict__ tgt,
        const int* __restrict__ clsrows, const int* __restrict__ rowOff,
        int ns, int N, int D, int C,
        unsigned short* __restrict__ Xg, float* __restrict__ sqg, float* __restrict__ sgg) {
    int s = blockIdx.x;
    int tid = threadIdx.x;
    __shared__ int ro[64];
    if (tid <= C) ro[tid] = rowOff[tid];
    __syncthreads();
    int c = 0;
    while (c + 1 <= C && ro[c + 1] <= s) c++;
    int g = clsrows[(size_t)c * N + (s - ro[c])];
    const float* row = (g < ns) ? src + (size_t)g * D : tgt + (size_t)(g - ns) * D;
    unsigned int* orow = (unsigned int*)(Xg + (size_t)s * D);
    float acc = 0.f;
    int iters = D / 512;
    for (int it = 0; it < iters; it++) {
        float2 v = *(const float2*)(row + it * 512 + tid * 2);
        acc += v.x * v.x + v.y * v.y;
        orow[it * 256 + tid] = f2bf(v.x) | (f2bf(v.y) << 16);
    }
    for (int o = 32; o; o >>= 1) acc += __shfl_down(acc, o);
    __shared__ float ls[4];
    if ((tid & 63) == 0) ls[tid >> 6] = acc;
    __syncthreads();
    if (tid == 0) {
        sqg[s] = ls[0] + ls[1] + ls[2] + ls[3];
        sgg[s] = (g < ns) ? 1.f : -1.f;
    }
}

// ---- per-class column sums (partial blocks + atomic f32) ----
__global__ void k_classum(const unsigned short* __restrict__ Xg,
                          const int* __restrict__ rowOff, int D,
                          float* __restrict__ classum) {
    int c = blockIdx.x;
    int chunk = blockIdx.y;     // 512-dim column chunk
    int split = blockIdx.z;     // row split (4)
    int b = rowOff[c], e = rowOff[c + 1];
    int n = e - b;
    int per = (n + 3) / 4;
    int r0 = split * per, r1 = min(n, r0 + per);
    int d = chunk * 512 + threadIdx.x * 2;
    float a0 = 0.f, a1 = 0.f;
    for (int r = r0; r < r1; r++) {
        unsigned int u = *(const unsigned int*)(Xg + (size_t)(b + r) * D + d);
        a0 += __uint_as_float(u << 16);
        a1 += __uint_as_float(u & 0xffff0000u);
    }
    if (r1 > r0) {
        atomicAdd(&classum[(size_t)c * D + d], a0);
        atomicAdd(&classum[(size_t)c * D + d + 1], a1);
    }
}

// ---- per-class bandwidth via closed form: sum_ij D2 = 2n*sum(sq) - 2*||sum x||^2 ----
__global__ void k_bwC(const float* __restrict__ sqg, const float* __restrict__ classum,
                      const int* __restrict__ rowOff, const int* __restrict__ present,
                      int D, float* __restrict__ invbw) {
    int c = blockIdx.x;
    int lane = threadIdx.x;    // 64
    int b = rowOff[c], e = rowOff[c + 1];
    int n = e - b;
    double sq = 0.0;
    for (int i = b + lane; i < e; i += 64) sq += (double)sqg[i];
    double snorm = 0.0;
    const float* cs = classum + (size_t)c * D;
    for (int d = lane; d < D; d += 64) { double v = (double)cs[d]; snorm += v * v; }
    for (int o = 32; o; o >>= 1) {
        sq += __shfl_down(sq, o);
        snorm += __shfl_down(snorm, o);
    }
    if (lane == 0) {
        double l2sum = 2.0 * (double)n * sq - 2.0 * snorm;
        double denom = (double)n * (double)n - (double)n;
        if (denom < 1.0) denom = 1.0;
        double bw = l2sum / denom / 4.0;   // bw_scale = KERNEL_MUL^(KERNEL_NUM//2) = 4
        bw = present[c] ? fmax(bw, 1e-20) : 1.0;
        double m = 1.0;
        for (int k = 0; k < 5; k++) { invbw[c * 8 + k] = (float)(1.0 / (bw * m)); m *= 2.0; }
    }
}

// ---- MFMA pair kernel: job = (class, 32x32 tile); 1 wave/job; fused exp epilogue ----
__global__ __launch_bounds__(64) void k_pairs(
        const unsigned short* __restrict__ Xg, const float* __restrict__ sqg,
        const float* __restrict__ sgg, const float* __restrict__ invbw,
        const int* __restrict__ jobOff, const int* __restrict__ tilesC,
        const int* __restrict__ rowOff, const int* __restrict__ nJobsP,
        int D, int C, double* __restrict__ contrib) {
    int lane = threadIdx.x;
    int nJobs = *nJobsP;
    int jo = (lane <= C) ? jobOff[lane] : 0x7fffffff;

    for (int job = blockIdx.x; job < nJobs; job += gridDim.x) {
        unsigned long long m = __ballot(jo <= job);
        int c = __popcll(m) - 1;                 // largest c with jobOff[c] <= job
        int jobbase = __shfl(jo, c);
        int T = tilesC[c];
        int t = job - jobbase;
        int ti = t / T, tj = t - ti * T;
        int base = rowOff[c];
        int n = rowOff[c + 1] - base;

        int kgrp = lane >> 4;                    // 0..3 -> k-offset kgrp*8
        int lr = lane & 15;
        int riA0 = min(ti * TILE + lr, n - 1);
        int riA1 = min(ti * TILE + lr + 16, n - 1);
        int riB0 = min(tj * TILE + lr, n - 1);
        int riB1 = min(tj * TILE + lr + 16, n - 1);
        const unsigned short* pA0 = Xg + (size_t)(base + riA0) * D + kgrp * 8;
        const unsigned short* pA1 = Xg + (size_t)(base + riA1) * D + kgrp * 8;
        const unsigned short* pB0 = Xg + (size_t)(base + riB0) * D + kgrp * 8;
        const unsigned short* pB1 = Xg + (size_t)(base + riB1) * D + kgrp * 8;

        f32x4 acc[2][2];
        acc[0][0] = (f32x4){0.f, 0.f, 0.f, 0.f};
        acc[0][1] = acc[0][0]; acc[1][0] = acc[0][0]; acc[1][1] = acc[0][0];

        #pragma unroll 4
        for (int k0 = 0; k0 < D; k0 += 32) {
            bf16x8 a0 = *(const bf16x8*)(pA0 + k0);
            bf16x8 a1 = *(const bf16x8*)(pA1 + k0);
            bf16x8 b0 = *(const bf16x8*)(pB0 + k0);
            bf16x8 b1 = *(const bf16x8*)(pB1 + k0);
            acc[0][0] = __builtin_amdgcn_mfma_f32_16x16x32_bf16(a0, b0, acc[0][0], 0, 0, 0);
            acc[0][1] = __builtin_amdgcn_mfma_f32_16x16x32_bf16(a0, b1, acc[0][1], 0, 0, 0);
            acc[1][0] = __builtin_amdgcn_mfma_f32_16x16x32_bf16(a1, b0, acc[1][0], 0, 0, 0);
            acc[1][1] = __builtin_amdgcn_mfma_f32_16x16x32_bf16(a1, b1, acc[1][1], 0, 0, 0);
        }

        float ib0 = invbw[c * 8 + 0], ib1 = invbw[c * 8 + 1], ib2 = invbw[c * 8 + 2];
        float ib3 = invbw[c * 8 + 3], ib4 = invbw[c * 8 + 4];

        // C/D layout: col = lane&15, row = (lane>>4)*4 + reg  [m89-verified]
        int crow = (lane >> 4) * 4;
        float tsum = 0.f;
        #pragma unroll
        for (int fj = 0; fj < 2; fj++) {
            int lj = fj * 16 + lr + tj * TILE;
            bool vj = lj < n;
            int cj = base + (vj ? lj - tj * TILE + tj * TILE : 0);
            cj = base + (vj ? lj : 0);
            float sB = sqg[cj];
            float gB = sgg[cj];
            #pragma unroll
            for (int fi = 0; fi < 2; fi++) {
                #pragma unroll
                for (int r = 0; r < 4; r++) {
                    int li = fi * 16 + crow + r + ti * TILE;
                    bool vi = li < n;
                    int ci = base + (vi ? li : 0);
                    float sA = sqg[ci];
                    float gA = sgg[ci];
                    float a = acc[fi][fj][r];
                    float D2 = sA + sB - 2.f * a;
                    float e = expf(-D2 * ib0) + expf(-D2 * ib1) + expf(-D2 * ib2)
                            + expf(-D2 * ib3) + expf(-D2 * ib4);
                    tsum += (vi && vj) ? gA * gB * e : 0.f;
                }
            }
        }
        double dsum = (double)tsum;
        for (int o = 32; o; o >>= 1) dsum += __shfl_down(dsum, o);
        if (lane == 0) atomicAdd(&contrib[c], dsum);
    }
}

__global__ void k_final(const double* __restrict__ contrib, const int* __restrict__ present,
                        const double* __restrict__ inv_n2, int C, float* __restrict__ out) {
    int c = threadIdx.x;
    double l = 0.0, k = 0.0;
    if (c < C && present[c]) { l = contrib[c] * inv_n2[c]; k = 1.0; }
    for (int o = 32; o; o >>= 1) { l += __shfl_down(l, o); k += __shfl_down(k, o); }
    if (c == 0) out[0] = (float)(l / k);
}

extern "C" void kernel_launch(void* const* d_in, const int* in_sizes, int n_in,
                              void* d_out, int out_size, void* d_ws, size_t ws_size,
                              hipStream_t stream) {
    const float* src  = (const float*)d_in[0];
    const float* tgt  = (const float*)d_in[1];
    const int*   slab = (const int*)d_in[2];
    const float* tlab = (const float*)d_in[3];
    const int ns = in_sizes[2];
    const int D  = in_sizes[0] / ns;
    const int nt = in_sizes[1] / D;
    const int C  = in_sizes[3] / nt;
    const int N  = ns + nt;

    char* w = (char*)d_ws;
    size_t off = 0;
    auto take = [&](size_t bytes) -> char* {
        char* p = w + off;
        off = (off + bytes + 255) & ~(size_t)255;
        return p;
    };
    // --- zero region ---
    int*    cnt_src = (int*)take(C * sizeof(int));
    int*    fill    = (int*)take(C * sizeof(int));
    double* contrib = (double*)take(C * sizeof(double));
    float*  classum = (float*)take((size_t)C * D * sizeof(float));
    size_t zbytes = off;
    // --- rest ---
    int*    clsrows = (int*)take((size_t)C * N * sizeof(int));
    int*    rowOff  = (int*)take((C + 1) * sizeof(int));
    int*    jobOff  = (int*)take((C + 1) * sizeof(int));
    int*    tilesC  = (int*)take(C * sizeof(int));
    int*    present = (int*)take(C * sizeof(int));
    double* inv_n2  = (double*)take(C * sizeof(double));
    float*  invbw   = (float*)take((size_t)C * 8 * sizeof(float));
    int*    nJobsP  = (int*)take(sizeof(int));
    unsigned short* Xg = (unsigned short*)take((size_t)N * D * sizeof(unsigned short));
    float*  sqg     = (float*)take((size_t)N * sizeof(float));
    float*  sgg     = (float*)take((size_t)N * sizeof(float));
    (void)ws_size; (void)n_in; (void)out_size;

    hipMemsetAsync(d_ws, 0, zbytes, stream);
    k_prep<<<(N + 255) / 256, 256, 0, stream>>>(slab, tlab, ns, N, C, clsrows, cnt_src, fill);
    k_offsets<<<1, 64, 0, stream>>>(cnt_src, fill, C, rowOff, jobOff, tilesC, present,
                                    inv_n2, nJobsP);
    k_gather<<<N, 256, 0, stream>>>(src, tgt, clsrows, rowOff, ns, N, D, C, Xg, sqg, sgg);
    dim3 gcs(C, D / 512, 4);
    k_classum<<<gcs, 256, 0, stream>>>(Xg, rowOff, D, classum);
    k_bwC<<<C, 64, 0, stream>>>(sqg, classum, rowOff, present, D, invbw);
    k_pairs<<<1024, 64, 0, stream>>>(Xg, sqg, sgg, invbw, jobOff, tilesC, rowOff,
                                     nJobsP, D, C, contrib);
    k_final<<<1, 64, 0, stream>>>(contrib, present, inv_n2, C, (float*)d_out);
}